// Round 9
// baseline (51.072 us; speedup 1.0000x reference)
//
#include <hip/hip_runtime.h>
#include <hip/hip_bf16.h>

#define N 8192
#define D 128
#define JC 32                // j-chunks
#define JCH (N / JC)         // 256 cols per chunk
#define WROWS 128            // rows per wave (8 M-tiles, a[8][4] -> AGPRs)
#define NRG (N / WROWS)      // 64 row-groups
#define NLBL 100             // labels in [0,100)
#define LCH 128              // labelsum blocks
#define LR 64                // rows per labelsum block

#define K1F 14.426950408889634f    // 10 * log2(e)
#define K0F (-14.426950408889634f)

#if __has_builtin(__builtin_amdgcn_exp2f)
#define EXP2(x) __builtin_amdgcn_exp2f(x)
#else
#define EXP2(x) exp2f(x)
#endif

typedef __attribute__((ext_vector_type(8))) short bf16x8;
typedef __attribute__((ext_vector_type(4))) float f32x4;

// ---------------- Stage 0: row-normalize z -> bf16 zn, plus self-dot d_ii ----
__global__ __launch_bounds__(256) void znorm_kernel(const float* __restrict__ z,
                                                    ushort* __restrict__ zn,
                                                    float* __restrict__ dii) {
    const int wid  = threadIdx.x >> 6;
    const int lane = threadIdx.x & 63;
    const int row  = blockIdx.x * 4 + wid;       // grid = N/4 blocks
    const float2 v = reinterpret_cast<const float2*>(z + (size_t)row * D)[lane];
    float ss = v.x * v.x + v.y * v.y;
    #pragma unroll
    for (int m = 1; m < 64; m <<= 1) ss += __shfl_xor(ss, m);
    const float inv = 1.0f / fmaxf(sqrtf(ss), 1e-8f);
    __hip_bfloat16 b0 = __float2bfloat16(v.x * inv);
    __hip_bfloat16 b1 = __float2bfloat16(v.y * inv);
    ushort2 o;
    o.x = *reinterpret_cast<ushort*>(&b0);
    o.y = *reinterpret_cast<ushort*>(&b1);
    reinterpret_cast<ushort2*>(zn + (size_t)row * D)[lane] = o;
    const float f0 = __bfloat162float(b0), f1 = __bfloat162float(b1);
    float s2 = f0 * f0 + f1 * f1;
    #pragma unroll
    for (int m = 1; m < 64; m <<= 1) s2 += __shfl_xor(s2, m);
    if (lane == 0) dii[row] = s2;
}

// ---------------- Stage 0b: per-label sums + histogram (deterministic) ------
__global__ __launch_bounds__(256) void labelsum_kernel(const ushort* __restrict__ zn,
                                                       const int* __restrict__ y,
                                                       float* __restrict__ tpart,
                                                       float* __restrict__ cpart) {
    __shared__ float tl[2][NLBL][D];   // 102.4 KB
    __shared__ float ch[2][128];
    __shared__ int   ly[LR];
    const int h = threadIdx.x >> 7;
    const int d = threadIdx.x & 127;
    for (int c = 0; c < NLBL; ++c) tl[h][c][d] = 0.0f;
    if (threadIdx.x < LR) ly[threadIdx.x] = y[blockIdx.x * LR + threadIdx.x];
    __syncthreads();
    const int j0 = blockIdx.x * LR + h * 32;
    float cl = 0.0f;
    for (int j = 0; j < 32; ++j) {
        const int c = ly[h * 32 + j];
        __hip_bfloat16 hb;
        *reinterpret_cast<ushort*>(&hb) = zn[(size_t)(j0 + j) * D + d];
        tl[h][c][d] += __bfloat162float(hb);      // exclusive column: no race
        cl += (c == d) ? 1.0f : 0.0f;
    }
    ch[h][d] = cl;
    __syncthreads();
    const float* t0 = &tl[0][0][0];
    for (int idx = threadIdx.x; idx < NLBL * D; idx += 256)
        tpart[(size_t)blockIdx.x * NLBL * D + idx] = t0[idx] + t0[NLBL * D + idx];
    if (threadIdx.x < NLBL)
        cpart[blockIdx.x * NLBL + threadIdx.x] = ch[0][threadIdx.x] + ch[1][threadIdx.x];
}

// ---------------- Stage 0c: reduce partials (parallel over outputs) ---------
__global__ __launch_bounds__(256) void reduce_t_kernel(const float* __restrict__ tpart,
                                                       const float* __restrict__ cpart,
                                                       float* __restrict__ t,
                                                       float* __restrict__ cnt) {
    if (blockIdx.x < NLBL * D / 64) {
        __shared__ float s4[4][64];
        const int o  = blockIdx.x * 64 + (threadIdx.x & 63);
        const int sl = threadIdx.x >> 6;           // 4 slices x 32 chunks
        float s = 0.0f;
        #pragma unroll 8
        for (int b = sl * (LCH / 4); b < (sl + 1) * (LCH / 4); ++b)
            s += tpart[(size_t)b * NLBL * D + o];
        s4[sl][threadIdx.x & 63] = s;
        __syncthreads();
        if (threadIdx.x < 64)
            t[blockIdx.x * 64 + threadIdx.x] = s4[0][threadIdx.x] + s4[1][threadIdx.x] +
                                               s4[2][threadIdx.x] + s4[3][threadIdx.x];
    } else {
        const int c = threadIdx.x;
        if (c < NLBL) {
            float s = 0.0f;
            for (int b = 0; b < LCH; ++b) s += cpart[b * NLBL + c];
            cnt[c] = s;
        }
    }
}

// ---------------- Stage 1: streaming MFMA, high per-wave intensity ----------
// R8 structure (2048 independent waves, 128 rows x 256 cols per wave,
// a[8][4] in AGPRs, launch_bounds(256,2) -> 2 waves/SIMD) + ONE change:
// asm memory-clobber pins after each prefetch group. Loads cannot cross a
// memory clobber, so the compiler cannot sink the ping-pong loads down to
// their use site (R5 evidence it rewrites reg-level pipelines). compute()
// is register-only, so the clobber forces no reloads.
__global__ __launch_bounds__(256, 2) void supcon_main(const ushort* __restrict__ zn,
                                                      float* __restrict__ pZ) {
    const int wid  = threadIdx.x >> 6;
    const int lane = threadIdx.x & 63;
    const int g    = lane >> 4;      // 0..3
    const int lj   = lane & 15;
    const int gw   = blockIdx.x * 4 + wid;       // 0..2047
    const int rowGrp = gw >> 5;                  // 64 row-groups (block-shared)
    const int chunk  = gw & 31;                  // 32 col-chunks
    const int rowBase = rowGrp * WROWS;
    const int j0 = chunk * JCH;

    // B column stream: 16 cols per iter
    const ushort* jp = zn + (size_t)(j0 + lj) * D + g * 8;
    bf16x8 b0[4], b1[4];
    #pragma unroll
    for (int s = 0; s < 4; ++s) b0[s] = *reinterpret_cast<const bf16x8*>(jp + s * 32);

    // A fragments: 8 M-tiles x 4 K-steps (128 regs -> AGPR file)
    bf16x8 a[8][4];
    #pragma unroll
    for (int m = 0; m < 8; ++m) {
        const ushort* rp = zn + (size_t)(rowBase + m * 16 + lj) * D;
        #pragma unroll
        for (int s = 0; s < 4; ++s)
            a[m][s] = *reinterpret_cast<const bf16x8*>(rp + s * 32 + g * 8);
    }

    float Z[8][4];
    #pragma unroll
    for (int m = 0; m < 8; ++m)
        #pragma unroll
        for (int r = 0; r < 4; ++r) Z[m][r] = 0.0f;

    const f32x4 zero4 = {0.f, 0.f, 0.f, 0.f};
    auto compute = [&](const bf16x8* B) {
        #pragma unroll
        for (int m = 0; m < 8; ++m) {
            f32x4 acc = zero4;
            #pragma unroll
            for (int s = 0; s < 4; ++s)
                acc = __builtin_amdgcn_mfma_f32_16x16x32_bf16(a[m][s], B[s], acc, 0, 0, 0);
            #pragma unroll
            for (int r = 0; r < 4; ++r)
                Z[m][r] += EXP2(fmaf(acc[r], K1F, K0F));   // exp(10*dot - 10)
        }
    };

    const int NIT = JCH / 16;        // 16 iterations, 16 cols each
    #pragma unroll 1
    for (int it = 0; it < NIT; it += 2) {
        const ushort* jp1 = jp + 16 * D;             // tile it+1
        #pragma unroll
        for (int s = 0; s < 4; ++s) b1[s] = *reinterpret_cast<const bf16x8*>(jp1 + s * 32);
        asm volatile("" ::: "memory");               // pin b1 loads above compute(b0)
        compute(b0);
        if (it + 2 < NIT) {
            const ushort* jp2 = jp + 32 * D;         // tile it+2
            #pragma unroll
            for (int s = 0; s < 4; ++s) b0[s] = *reinterpret_cast<const bf16x8*>(jp2 + s * 32);
        }
        asm volatile("" ::: "memory");               // pin b0 loads above compute(b1)
        compute(b1);
        jp += 32 * D;
    }

    // sum the 16 cols within each lane group
    #pragma unroll
    for (int m = 0; m < 8; ++m)
        #pragma unroll
        for (int r = 0; r < 4; ++r)
            #pragma unroll
            for (int mk = 1; mk < 16; mk <<= 1)
                Z[m][r] += __shfl_xor(Z[m][r], mk);

    if (lj == 0) {
        #pragma unroll
        for (int m = 0; m < 8; ++m)
            #pragma unroll
            for (int r = 0; r < 4; ++r)
                pZ[chunk * N + rowBase + m * 16 + g * 4 + r] = Z[m][r];
    }
}

// ---------------- Stage 2: finalize loss ----------------
__global__ __launch_bounds__(256) void supcon_finalize(const ushort* __restrict__ zn,
                                                       const int* __restrict__ y,
                                                       const float* __restrict__ pZ,
                                                       const float* __restrict__ dii,
                                                       const float* __restrict__ t,
                                                       const float* __restrict__ cnt,
                                                       float* __restrict__ out) {
    const int wid  = threadIdx.x >> 6;
    const int lane = threadIdx.x & 63;
    const int row  = blockIdx.x * 4 + wid;
    const int c    = y[row];
    const ushort2 u = reinterpret_cast<const ushort2*>(zn + (size_t)row * D)[lane];
    const float2 tv = reinterpret_cast<const float2*>(t + (size_t)c * D)[lane];
    __hip_bfloat16 h0, h1;
    *reinterpret_cast<ushort*>(&h0) = u.x;
    *reinterpret_cast<ushort*>(&h1) = u.y;
    float dot = __bfloat162float(h0) * tv.x + __bfloat162float(h1) * tv.y;
    #pragma unroll
    for (int m = 1; m < 64; m <<= 1) dot += __shfl_xor(dot, m);
    float zs = (lane < JC) ? pZ[lane * N + row] : 0.0f;
    #pragma unroll
    for (int m = 1; m < JC; m <<= 1) zs += __shfl_xor(zs, m);
    if (lane == 0) {
        const float di = dii[row];
        const float zc = zs - EXP2(fmaf(di, K1F, K0F));   // remove self term
        const float cn = cnt[c] - 1.0f;                   // exclude self
        const float S  = dot - di;                        // exclude self
        const float denom = fmaxf(cn, 1.0f);
        const float lse   = 10.0f + logf(zc);
        out[row] = -(10.0f * S) / denom + (cn > 0.5f ? lse : 0.0f);
    }
}

extern "C" void kernel_launch(void* const* d_in, const int* in_sizes, int n_in,
                              void* d_out, int out_size, void* d_ws, size_t ws_size,
                              hipStream_t stream) {
    const float* z = (const float*)d_in[0];
    const int*   y = (const int*)d_in[1];
    float* out = (float*)d_out;

    // ws layout (~9.7 MB)
    ushort* zn    = (ushort*)d_ws;                                  // 2 MB
    float*  dii   = (float*)((char*)d_ws + (size_t)N * D * 2);      // 32 KB
    float*  tpart = dii + N;                                        // 6.55 MB
    float*  cpart = tpart + (size_t)LCH * NLBL * D;                 // 51.2 KB
    float*  t     = cpart + (size_t)LCH * NLBL;                     // 51.2 KB
    float*  cnt   = t + (size_t)NLBL * D;                           // 400 B
    float*  pZ    = cnt + NLBL;                                     // 1 MB

    znorm_kernel<<<N / 4, 256, 0, stream>>>(z, zn, dii);
    labelsum_kernel<<<LCH, 256, 0, stream>>>(zn, y, tpart, cpart);
    reduce_t_kernel<<<NLBL * D / 64 + 1, 256, 0, stream>>>(tpart, cpart, t, cnt);
    supcon_main<<<(NRG * JC) / 4, 256, 0, stream>>>(zn, pZ);
    supcon_finalize<<<N / 4, 256, 0, stream>>>(zn, y, pZ, dii, t, cnt, out);
}

// Round 10
// 50.546 us; speedup vs baseline: 1.0104x; 1.0104x over previous
//
#include <hip/hip_runtime.h>
#include <hip/hip_bf16.h>

#define N 8192
#define D 128
#define JC 32                // j-chunks
#define JCH (N / JC)         // 256 cols per chunk
#define WROWS 128            // rows per wave (8 M-tiles, a[8][4] -> AGPRs)
#define NRG (N / WROWS)      // 64 row-groups
#define NLBL 100             // labels in [0,100)
#define LCH 128              // labelsum blocks
#define LR 64                // rows per labelsum block

#define K1F 14.426950408889634f    // 10 * log2(e)
#define K0F (-14.426950408889634f)

#if __has_builtin(__builtin_amdgcn_exp2f)
#define EXP2(x) __builtin_amdgcn_exp2f(x)
#else
#define EXP2(x) exp2f(x)
#endif

typedef __attribute__((ext_vector_type(8))) short bf16x8;
typedef __attribute__((ext_vector_type(4))) float f32x4;

// ---------------- Stage 0: row-normalize z -> bf16 zn, plus self-dot d_ii ----
__global__ __launch_bounds__(256) void znorm_kernel(const float* __restrict__ z,
                                                    ushort* __restrict__ zn,
                                                    float* __restrict__ dii) {
    const int wid  = threadIdx.x >> 6;
    const int lane = threadIdx.x & 63;
    const int row  = blockIdx.x * 4 + wid;       // grid = N/4 blocks
    const float2 v = reinterpret_cast<const float2*>(z + (size_t)row * D)[lane];
    float ss = v.x * v.x + v.y * v.y;
    #pragma unroll
    for (int m = 1; m < 64; m <<= 1) ss += __shfl_xor(ss, m);
    const float inv = 1.0f / fmaxf(sqrtf(ss), 1e-8f);
    __hip_bfloat16 b0 = __float2bfloat16(v.x * inv);
    __hip_bfloat16 b1 = __float2bfloat16(v.y * inv);
    ushort2 o;
    o.x = *reinterpret_cast<ushort*>(&b0);
    o.y = *reinterpret_cast<ushort*>(&b1);
    reinterpret_cast<ushort2*>(zn + (size_t)row * D)[lane] = o;
    const float f0 = __bfloat162float(b0), f1 = __bfloat162float(b1);
    float s2 = f0 * f0 + f1 * f1;
    #pragma unroll
    for (int m = 1; m < 64; m <<= 1) s2 += __shfl_xor(s2, m);
    if (lane == 0) dii[row] = s2;
}

// ---------------- Stage 0b: per-label sums + histogram (deterministic) ------
__global__ __launch_bounds__(256) void labelsum_kernel(const ushort* __restrict__ zn,
                                                       const int* __restrict__ y,
                                                       float* __restrict__ tpart,
                                                       float* __restrict__ cpart) {
    __shared__ float tl[2][NLBL][D];   // 102.4 KB
    __shared__ float ch[2][128];
    __shared__ int   ly[LR];
    const int h = threadIdx.x >> 7;
    const int d = threadIdx.x & 127;
    for (int c = 0; c < NLBL; ++c) tl[h][c][d] = 0.0f;
    if (threadIdx.x < LR) ly[threadIdx.x] = y[blockIdx.x * LR + threadIdx.x];
    __syncthreads();
    const int j0 = blockIdx.x * LR + h * 32;
    float cl = 0.0f;
    for (int j = 0; j < 32; ++j) {
        const int c = ly[h * 32 + j];
        __hip_bfloat16 hb;
        *reinterpret_cast<ushort*>(&hb) = zn[(size_t)(j0 + j) * D + d];
        tl[h][c][d] += __bfloat162float(hb);      // exclusive column: no race
        cl += (c == d) ? 1.0f : 0.0f;
    }
    ch[h][d] = cl;
    __syncthreads();
    const float* t0 = &tl[0][0][0];
    for (int idx = threadIdx.x; idx < NLBL * D; idx += 256)
        tpart[(size_t)blockIdx.x * NLBL * D + idx] = t0[idx] + t0[NLBL * D + idx];
    if (threadIdx.x < NLBL)
        cpart[blockIdx.x * NLBL + threadIdx.x] = ch[0][threadIdx.x] + ch[1][threadIdx.x];
}

// ---------------- Stage 0c: reduce partials (parallel over outputs) ---------
__global__ __launch_bounds__(256) void reduce_t_kernel(const float* __restrict__ tpart,
                                                       const float* __restrict__ cpart,
                                                       float* __restrict__ t,
                                                       float* __restrict__ cnt) {
    if (blockIdx.x < NLBL * D / 64) {
        __shared__ float s4[4][64];
        const int o  = blockIdx.x * 64 + (threadIdx.x & 63);
        const int sl = threadIdx.x >> 6;           // 4 slices x 32 chunks
        float s = 0.0f;
        #pragma unroll 8
        for (int b = sl * (LCH / 4); b < (sl + 1) * (LCH / 4); ++b)
            s += tpart[(size_t)b * NLBL * D + o];
        s4[sl][threadIdx.x & 63] = s;
        __syncthreads();
        if (threadIdx.x < 64)
            t[blockIdx.x * 64 + threadIdx.x] = s4[0][threadIdx.x] + s4[1][threadIdx.x] +
                                               s4[2][threadIdx.x] + s4[3][threadIdx.x];
    } else {
        const int c = threadIdx.x;
        if (c < NLBL) {
            float s = 0.0f;
            for (int b = 0; b < LCH; ++b) s += cpart[b * NLBL + c];
            cnt[c] = s;
        }
    }
}

// ---------------- Stage 1: streaming MFMA, k-outer/m-inner ILP --------------
// R8/R9 structure (2048 independent waves, 128 rows x 256 cols per wave,
// a[8][4] in AGPRs, launch_bounds(256,2) -> 2 waves/SIMD) + ONE change:
// MFMA loop nest is k-OUTER / m-INNER over an acc[8] array, exps batched
// after. Consecutive MFMAs are independent (dep distance = 8 instrs), so
// the matrix pipe saturates via intra-wave ILP; R7-R9's m-outer form was a
// 4-deep dependent chain + in-order exp behind it (MfmaUtil 16% @1 wave).
__global__ __launch_bounds__(256, 2) void supcon_main(const ushort* __restrict__ zn,
                                                      float* __restrict__ pZ) {
    const int wid  = threadIdx.x >> 6;
    const int lane = threadIdx.x & 63;
    const int g    = lane >> 4;      // 0..3
    const int lj   = lane & 15;
    const int gw   = blockIdx.x * 4 + wid;       // 0..2047
    const int rowGrp = gw >> 5;                  // 64 row-groups (block-shared)
    const int chunk  = gw & 31;                  // 32 col-chunks
    const int rowBase = rowGrp * WROWS;
    const int j0 = chunk * JCH;

    // B column stream: 16 cols per iter
    const ushort* jp = zn + (size_t)(j0 + lj) * D + g * 8;
    bf16x8 b0[4], b1[4];
    #pragma unroll
    for (int s = 0; s < 4; ++s) b0[s] = *reinterpret_cast<const bf16x8*>(jp + s * 32);

    // A fragments: 8 M-tiles x 4 K-steps (128 regs -> AGPR file)
    bf16x8 a[8][4];
    #pragma unroll
    for (int m = 0; m < 8; ++m) {
        const ushort* rp = zn + (size_t)(rowBase + m * 16 + lj) * D;
        #pragma unroll
        for (int s = 0; s < 4; ++s)
            a[m][s] = *reinterpret_cast<const bf16x8*>(rp + s * 32 + g * 8);
    }

    float Z[8][4];
    #pragma unroll
    for (int m = 0; m < 8; ++m)
        #pragma unroll
        for (int r = 0; r < 4; ++r) Z[m][r] = 0.0f;

    const f32x4 zero4 = {0.f, 0.f, 0.f, 0.f};
    auto compute = [&](const bf16x8* B) {
        f32x4 acc[8];
        #pragma unroll
        for (int m = 0; m < 8; ++m) acc[m] = zero4;
        // k-outer / m-inner: adjacent MFMAs independent -> full ILP
        #pragma unroll
        for (int s = 0; s < 4; ++s)
            #pragma unroll
            for (int m = 0; m < 8; ++m)
                acc[m] = __builtin_amdgcn_mfma_f32_16x16x32_bf16(a[m][s], B[s], acc[m], 0, 0, 0);
        // batched epilogue: exps overlap the other wave's MFMA phase
        #pragma unroll
        for (int m = 0; m < 8; ++m)
            #pragma unroll
            for (int r = 0; r < 4; ++r)
                Z[m][r] += EXP2(fmaf(acc[m][r], K1F, K0F));   // exp(10*dot - 10)
    };

    const int NIT = JCH / 16;        // 16 iterations, 16 cols each
    #pragma unroll 1
    for (int it = 0; it < NIT; it += 2) {
        const ushort* jp1 = jp + 16 * D;             // tile it+1
        #pragma unroll
        for (int s = 0; s < 4; ++s) b1[s] = *reinterpret_cast<const bf16x8*>(jp1 + s * 32);
        asm volatile("" ::: "memory");               // pin b1 loads above compute(b0)
        compute(b0);
        if (it + 2 < NIT) {
            const ushort* jp2 = jp + 32 * D;         // tile it+2
            #pragma unroll
            for (int s = 0; s < 4; ++s) b0[s] = *reinterpret_cast<const bf16x8*>(jp2 + s * 32);
        }
        asm volatile("" ::: "memory");               // pin b0 loads above compute(b1)
        compute(b1);
        jp += 32 * D;
    }

    // sum the 16 cols within each lane group
    #pragma unroll
    for (int m = 0; m < 8; ++m)
        #pragma unroll
        for (int r = 0; r < 4; ++r)
            #pragma unroll
            for (int mk = 1; mk < 16; mk <<= 1)
                Z[m][r] += __shfl_xor(Z[m][r], mk);

    if (lj == 0) {
        #pragma unroll
        for (int m = 0; m < 8; ++m)
            #pragma unroll
            for (int r = 0; r < 4; ++r)
                pZ[chunk * N + rowBase + m * 16 + g * 4 + r] = Z[m][r];
    }
}

// ---------------- Stage 2: finalize loss ----------------
__global__ __launch_bounds__(256) void supcon_finalize(const ushort* __restrict__ zn,
                                                       const int* __restrict__ y,
                                                       const float* __restrict__ pZ,
                                                       const float* __restrict__ dii,
                                                       const float* __restrict__ t,
                                                       const float* __restrict__ cnt,
                                                       float* __restrict__ out) {
    const int wid  = threadIdx.x >> 6;
    const int lane = threadIdx.x & 63;
    const int row  = blockIdx.x * 4 + wid;
    const int c    = y[row];
    const ushort2 u = reinterpret_cast<const ushort2*>(zn + (size_t)row * D)[lane];
    const float2 tv = reinterpret_cast<const float2*>(t + (size_t)c * D)[lane];
    __hip_bfloat16 h0, h1;
    *reinterpret_cast<ushort*>(&h0) = u.x;
    *reinterpret_cast<ushort*>(&h1) = u.y;
    float dot = __bfloat162float(h0) * tv.x + __bfloat162float(h1) * tv.y;
    #pragma unroll
    for (int m = 1; m < 64; m <<= 1) dot += __shfl_xor(dot, m);
    float zs = (lane < JC) ? pZ[lane * N + row] : 0.0f;
    #pragma unroll
    for (int m = 1; m < JC; m <<= 1) zs += __shfl_xor(zs, m);
    if (lane == 0) {
        const float di = dii[row];
        const float zc = zs - EXP2(fmaf(di, K1F, K0F));   // remove self term
        const float cn = cnt[c] - 1.0f;                   // exclude self
        const float S  = dot - di;                        // exclude self
        const float denom = fmaxf(cn, 1.0f);
        const float lse   = 10.0f + logf(zc);
        out[row] = -(10.0f * S) / denom + (cn > 0.5f ? lse : 0.0f);
    }
}

extern "C" void kernel_launch(void* const* d_in, const int* in_sizes, int n_in,
                              void* d_out, int out_size, void* d_ws, size_t ws_size,
                              hipStream_t stream) {
    const float* z = (const float*)d_in[0];
    const int*   y = (const int*)d_in[1];
    float* out = (float*)d_out;

    // ws layout (~9.7 MB)
    ushort* zn    = (ushort*)d_ws;                                  // 2 MB
    float*  dii   = (float*)((char*)d_ws + (size_t)N * D * 2);      // 32 KB
    float*  tpart = dii + N;                                        // 6.55 MB
    float*  cpart = tpart + (size_t)LCH * NLBL * D;                 // 51.2 KB
    float*  t     = cpart + (size_t)LCH * NLBL;                     // 51.2 KB
    float*  cnt   = t + (size_t)NLBL * D;                           // 400 B
    float*  pZ    = cnt + NLBL;                                     // 1 MB

    znorm_kernel<<<N / 4, 256, 0, stream>>>(z, zn, dii);
    labelsum_kernel<<<LCH, 256, 0, stream>>>(zn, y, tpart, cpart);
    reduce_t_kernel<<<NLBL * D / 64 + 1, 256, 0, stream>>>(tpart, cpart, t, cnt);
    supcon_main<<<(NRG * JC) / 4, 256, 0, stream>>>(zn, pZ);
    supcon_finalize<<<N / 4, 256, 0, stream>>>(zn, y, pZ, dii, t, cnt, out);
}